// Round 1
// baseline (228.131 us; speedup 1.0000x reference)
//
#include <hip/hip_runtime.h>
#include <math.h>

#define HID 128
#define ATT 64
#define HOPS 8
#define T_ 64
#define N_ 64
#define B_ 64
#define L_ 4096

static constexpr size_t OFF_A     = (size_t)B_ * N_ * T_;              // 262144
static constexpr size_t OFF_NEIGH = OFF_A + (size_t)B_ * HOPS * L_;    // 2359296
static constexpr size_t OFF_PENAL = OFF_NEIGH + (size_t)B_ * L_ * HID; // 35913728

// ---------------- K1: fused H -> s1 -> tanh -> s2 (staged into A region), + neigh copy ----------
__global__ __launch_bounds__(256)
void k1_s2(const float* __restrict__ node, const float* __restrict__ neigh,
           const int* __restrict__ nnum, const float* __restrict__ W1,
           const float* __restrict__ b1, const float* __restrict__ W2,
           const float* __restrict__ b2, float* __restrict__ out)
{
    __shared__ float nodeS[T_][HID + 4];   // +4 keeps float4 alignment; 8-way bank alias is negligible here
    const int tid = threadIdx.x;
    const int b  = blockIdx.x >> 4;        // 16 blocks per batch (4096 rows / 256)
    const int l0 = (blockIdx.x & 15) << 8;

    const float4* nsrc = (const float4*)(node + (size_t)b * T_ * HID);
    for (int i = tid; i < T_ * HID / 4; i += 256) {
        int t = i >> 5, c = i & 31;
        *(float4*)&nodeS[t][c * 4] = nsrc[i];
    }
    __syncthreads();

    const int l = l0 + tid;
    const int t = tid & 63;                 // l % T  (l0 is a multiple of 256)
    const float inv_scale = 1.0f / sqrtf((float)nnum[0]);
    const float* nrow = neigh + ((size_t)b * L_ + l) * HID;
    float*       orow = out + OFF_NEIGH + ((size_t)b * L_ + l) * HID;

    float acc[ATT];
    #pragma unroll
    for (int a = 0; a < ATT; ++a) acc[a] = 0.0f;

    #pragma unroll 1
    for (int d0 = 0; d0 < HID; d0 += 32) {
        float4 v[8];
        #pragma unroll
        for (int cv = 0; cv < 8; ++cv) v[cv] = *(const float4*)(nrow + d0 + cv * 4);
        float h[32];
        #pragma unroll
        for (int d = 0; d < 32; ++d) {
            float x = ((const float*)v)[d];
            h[d] = x * nodeS[t][d0 + d];
        }
        #pragma unroll
        for (int cv = 0; cv < 8; ++cv) *(float4*)(orow + d0 + cv * 4) = v[cv];
        // s1 partial GEMM: W1 indices are wave-uniform -> scalar loads, SGPR operand in v_fmac
        #pragma unroll
        for (int a = 0; a < ATT; ++a) {
            float s = acc[a];
            #pragma unroll
            for (int d = 0; d < 32; ++d) s = fmaf(h[d], W1[a * HID + d0 + d], s);
            acc[a] = s;
        }
    }

    float th[ATT];
    #pragma unroll
    for (int a = 0; a < ATT; ++a) {
        float s1v = (acc[a] + b1[a]) * inv_scale;
        // tanh(x) = 1 - 2/(exp(2x)+1): safe at +/-inf, 1 hw exp
        th[a] = 1.0f - 2.0f / (__expf(2.0f * s1v) + 1.0f);
    }
    #pragma unroll
    for (int hh = 0; hh < HOPS; ++hh) {
        float s = b2[hh];
        #pragma unroll
        for (int a = 0; a < ATT; ++a) s = fmaf(th[a], W2[hh * ATT + a], s);
        out[OFF_A + (size_t)b * HOPS * L_ + (size_t)hh * L_ + l] = s;   // coalesced per hh
    }
}

// ---------------- reductions helpers ----------------
__device__ __forceinline__ float waveMax(float v) {
    #pragma unroll
    for (int o = 32; o > 0; o >>= 1) v = fmaxf(v, __shfl_xor(v, o));
    return v;
}
__device__ __forceinline__ float waveSum(float v) {
    #pragma unroll
    for (int o = 32; o > 0; o >>= 1) v += __shfl_xor(v, o);
    return v;
}

// ---------------- K2: per-(b,h) softmax stats over L ----------------
__global__ __launch_bounds__(256)
void k2_stats(const float* __restrict__ out, float* __restrict__ stats)
{
    const int bh = blockIdx.x;                         // 0..511
    const float* row = out + OFF_A + (size_t)bh * L_;  // contiguous 4096 floats
    const int tid = threadIdx.x;
    __shared__ float red[8];
    float m = -3.4e38f;
    for (int i = tid; i < L_; i += 256) m = fmaxf(m, row[i]);
    m = waveMax(m);
    if ((tid & 63) == 0) red[tid >> 6] = m;
    __syncthreads();
    const float M = fmaxf(fmaxf(red[0], red[1]), fmaxf(red[2], red[3]));
    float s = 0.0f;
    for (int i = tid; i < L_; i += 256) s += __expf(row[i] - M);
    s = waveSum(s);
    if ((tid & 63) == 0) red[4 + (tid >> 6)] = s;
    __syncthreads();
    if (tid == 0) {
        stats[bh * 2]     = M;
        stats[bh * 2 + 1] = red[4] + red[5] + red[6] + red[7];
    }
}

// ---------------- K3: in-place A = softmax, BW = sum_h A, AAT partials ----------------
__global__ __launch_bounds__(256)
void k3_soft(float* __restrict__ out, const float* __restrict__ stats, float* __restrict__ aat)
{
    const int b = blockIdx.x;          // one block per batch -> exclusive owner of aat[b]
    const int tid = threadIdx.x;
    float* A0 = out + OFF_A + (size_t)b * HOPS * L_;
    float* BW = out + (size_t)b * L_;
    float M[HOPS], R[HOPS];
    #pragma unroll
    for (int hh = 0; hh < HOPS; ++hh) {
        M[hh] = stats[(b * HOPS + hh) * 2];
        R[hh] = 1.0f / stats[(b * HOPS + hh) * 2 + 1];
    }
    float p[36];
    #pragma unroll
    for (int i = 0; i < 36; ++i) p[i] = 0.0f;
    for (int l = tid; l < L_; l += 256) {
        float e[HOPS]; float srow = 0.0f;
        #pragma unroll
        for (int hh = 0; hh < HOPS; ++hh) {
            float v = __expf(A0[hh * L_ + l] - M[hh]) * R[hh];
            e[hh] = v; srow += v;
        }
        #pragma unroll
        for (int hh = 0; hh < HOPS; ++hh) A0[hh * L_ + l] = e[hh];
        BW[l] = srow;
        int i = 0;
        #pragma unroll
        for (int hh = 0; hh < HOPS; ++hh) {
            #pragma unroll
            for (int g = hh; g < HOPS; ++g) { p[i] = fmaf(e[hh], e[g], p[i]); ++i; }
        }
    }
    #pragma unroll
    for (int i = 0; i < 36; ++i) p[i] = waveSum(p[i]);
    __shared__ float red[4][36];
    const int wv = tid >> 6, ln = tid & 63;
    if (ln == 0) {
        #pragma unroll
        for (int i = 0; i < 36; ++i) red[wv][i] = p[i];
    }
    __syncthreads();
    if (tid < 36) {
        float s = red[0][tid] + red[1][tid] + red[2][tid] + red[3][tid];
        int h = 0, i = tid;
        while (i >= HOPS - h) { i -= (HOPS - h); ++h; }
        int g = h + i;
        aat[b * 64 + h * 8 + g] = s;
        aat[b * 64 + g * 8 + h] = s;
    }
}

// ---------------- K4: penal = sum((AAT - I)^2) ----------------
__global__ __launch_bounds__(256)
void k4_penal(const float* __restrict__ aat, float* __restrict__ out)
{
    const int tid = threadIdx.x;
    float s = 0.0f;
    for (int i = tid; i < B_ * 64; i += 256) {
        int hg = i & 63;
        float d = aat[i] - (((hg >> 3) == (hg & 7)) ? 1.0f : 0.0f);
        s = fmaf(d, d, s);
    }
    s = waveSum(s);
    __shared__ float red[4];
    if ((tid & 63) == 0) red[tid >> 6] = s;
    __syncthreads();
    if (tid == 0) out[OFF_PENAL] = red[0] + red[1] + red[2] + red[3];
}

extern "C" void kernel_launch(void* const* d_in, const int* in_sizes, int n_in,
                              void* d_out, int out_size, void* d_ws, size_t ws_size,
                              hipStream_t stream) {
    const float* node  = (const float*)d_in[0];
    const float* neigh = (const float*)d_in[1];
    const int*   nnum  = (const int*)d_in[2];   // reads low 32 bits of elem 0: ok for i32 or i64 LE
    const float* W1    = (const float*)d_in[3];
    const float* b1    = (const float*)d_in[4];
    const float* W2    = (const float*)d_in[5];
    const float* b2    = (const float*)d_in[6];
    float* out   = (float*)d_out;
    float* stats = (float*)d_ws;          // 512*2 floats
    float* aat   = stats + 1024;          // 64*64 floats

    k1_s2 <<<B_ * 16, 256, 0, stream>>>(node, neigh, nnum, W1, b1, W2, b2, out);
    k2_stats<<<B_ * HOPS, 256, 0, stream>>>(out, stats);
    k3_soft <<<B_, 256, 0, stream>>>(out, stats, aat);
    k4_penal<<<1, 256, 0, stream>>>(aat, out);
}

// Round 2
// 173.543 us; speedup vs baseline: 1.3146x; 1.3146x over previous
//
#include <hip/hip_runtime.h>
#include <math.h>

#define HID 128
#define ATT 64
#define HOPS 8
#define T_ 64
#define N_ 64
#define B_ 64
#define L_ 4096

static constexpr size_t OFF_A     = (size_t)B_ * N_ * T_;              // 262144
static constexpr size_t OFF_NEIGH = OFF_A + (size_t)B_ * HOPS * L_;    // 2359296
static constexpr size_t OFF_PENAL = OFF_NEIGH + (size_t)B_ * L_ * HID; // 35913728

// ---------------- K1: fused H -> s1 -> tanh -> s2 (staged into A region), + neigh copy ----------
// d-chunk = 16 floats keeps live set at acc[64]+h[16]+addr ~ 100 VGPRs;
// __launch_bounds__(256,4) caps alloc at 128 VGPRs (no spill) and matches the
// 4-blocks/CU LDS limit (33 KB/block).
__global__ __launch_bounds__(256, 4)
void k1_s2(const float* __restrict__ node, const float* __restrict__ neigh,
           const int* __restrict__ nnum, const float* __restrict__ W1,
           const float* __restrict__ b1, const float* __restrict__ W2,
           const float* __restrict__ b2, float* __restrict__ out)
{
    __shared__ float nodeS[T_][HID + 4];
    const int tid = threadIdx.x;
    const int b  = blockIdx.x >> 4;        // 16 blocks per batch (4096 rows / 256)
    const int l0 = (blockIdx.x & 15) << 8;

    const float4* nsrc = (const float4*)(node + (size_t)b * T_ * HID);
    for (int i = tid; i < T_ * HID / 4; i += 256) {
        int t = i >> 5, c = i & 31;
        *(float4*)&nodeS[t][c * 4] = nsrc[i];
    }
    __syncthreads();

    const int l = l0 + tid;
    const int t = tid & 63;                 // l % T  (l0 is a multiple of 256)
    const float inv_scale = 1.0f / sqrtf((float)nnum[0]);
    const float* nrow = neigh + ((size_t)b * L_ + l) * HID;
    float*       orow = out + OFF_NEIGH + ((size_t)b * L_ + l) * HID;

    float acc[ATT];
    #pragma unroll
    for (int a = 0; a < ATT; ++a) acc[a] = 0.0f;

    #pragma unroll 1
    for (int d0 = 0; d0 < HID; d0 += 16) {
        float4 v[4];
        #pragma unroll
        for (int cv = 0; cv < 4; ++cv) v[cv] = *(const float4*)(nrow + d0 + cv * 4);
        float h[16];
        #pragma unroll
        for (int d = 0; d < 16; ++d) {
            float x = ((const float*)v)[d];
            h[d] = x * nodeS[t][d0 + d];
        }
        #pragma unroll
        for (int cv = 0; cv < 4; ++cv) *(float4*)(orow + d0 + cv * 4) = v[cv];
        // s1 partial GEMM: W1 indices are wave-uniform -> s_load_dwordx16 per a,
        // FMA with SGPR operand (zero VGPR cost for W1).
        #pragma unroll
        for (int a = 0; a < ATT; ++a) {
            float s = acc[a];
            #pragma unroll
            for (int d = 0; d < 16; ++d) s = fmaf(h[d], W1[a * HID + d0 + d], s);
            acc[a] = s;
        }
    }

    float th[ATT];
    #pragma unroll
    for (int a = 0; a < ATT; ++a) {
        float s1v = (acc[a] + b1[a]) * inv_scale;
        // tanh(x) = 1 - 2/(exp(2x)+1): safe at +/-inf, 1 hw exp
        th[a] = 1.0f - 2.0f / (__expf(2.0f * s1v) + 1.0f);
    }
    #pragma unroll
    for (int hh = 0; hh < HOPS; ++hh) {
        float s = b2[hh];
        #pragma unroll
        for (int a = 0; a < ATT; ++a) s = fmaf(th[a], W2[hh * ATT + a], s);
        out[OFF_A + (size_t)b * HOPS * L_ + (size_t)hh * L_ + l] = s;   // coalesced per hh
    }
}

// ---------------- reductions helpers ----------------
__device__ __forceinline__ float waveMax(float v) {
    #pragma unroll
    for (int o = 32; o > 0; o >>= 1) v = fmaxf(v, __shfl_xor(v, o));
    return v;
}
__device__ __forceinline__ float waveSum(float v) {
    #pragma unroll
    for (int o = 32; o > 0; o >>= 1) v += __shfl_xor(v, o);
    return v;
}

// ---------------- K2: per-(b,h) softmax stats over L ----------------
__global__ __launch_bounds__(256)
void k2_stats(const float* __restrict__ out, float* __restrict__ stats)
{
    const int bh = blockIdx.x;                         // 0..511
    const float* row = out + OFF_A + (size_t)bh * L_;  // contiguous 4096 floats
    const int tid = threadIdx.x;
    __shared__ float red[8];
    float m = -3.4e38f;
    for (int i = tid; i < L_; i += 256) m = fmaxf(m, row[i]);
    m = waveMax(m);
    if ((tid & 63) == 0) red[tid >> 6] = m;
    __syncthreads();
    const float M = fmaxf(fmaxf(red[0], red[1]), fmaxf(red[2], red[3]));
    float s = 0.0f;
    for (int i = tid; i < L_; i += 256) s += __expf(row[i] - M);
    s = waveSum(s);
    if ((tid & 63) == 0) red[4 + (tid >> 6)] = s;
    __syncthreads();
    if (tid == 0) {
        stats[bh * 2]     = M;
        stats[bh * 2 + 1] = red[4] + red[5] + red[6] + red[7];
    }
}

// ---------------- K3: in-place A = softmax, BW = sum_h A, AAT partials ----------------
__global__ __launch_bounds__(256)
void k3_soft(float* __restrict__ out, const float* __restrict__ stats, float* __restrict__ aat)
{
    const int b = blockIdx.x;          // one block per batch -> exclusive owner of aat[b]
    const int tid = threadIdx.x;
    float* A0 = out + OFF_A + (size_t)b * HOPS * L_;
    float* BW = out + (size_t)b * L_;
    float M[HOPS], R[HOPS];
    #pragma unroll
    for (int hh = 0; hh < HOPS; ++hh) {
        M[hh] = stats[(b * HOPS + hh) * 2];
        R[hh] = 1.0f / stats[(b * HOPS + hh) * 2 + 1];
    }
    float p[36];
    #pragma unroll
    for (int i = 0; i < 36; ++i) p[i] = 0.0f;
    for (int l = tid; l < L_; l += 256) {
        float e[HOPS]; float srow = 0.0f;
        #pragma unroll
        for (int hh = 0; hh < HOPS; ++hh) {
            float v = __expf(A0[hh * L_ + l] - M[hh]) * R[hh];
            e[hh] = v; srow += v;
        }
        #pragma unroll
        for (int hh = 0; hh < HOPS; ++hh) A0[hh * L_ + l] = e[hh];
        BW[l] = srow;
        int i = 0;
        #pragma unroll
        for (int hh = 0; hh < HOPS; ++hh) {
            #pragma unroll
            for (int g = hh; g < HOPS; ++g) { p[i] = fmaf(e[hh], e[g], p[i]); ++i; }
        }
    }
    #pragma unroll
    for (int i = 0; i < 36; ++i) p[i] = waveSum(p[i]);
    __shared__ float red[4][36];
    const int wv = tid >> 6, ln = tid & 63;
    if (ln == 0) {
        #pragma unroll
        for (int i = 0; i < 36; ++i) red[wv][i] = p[i];
    }
    __syncthreads();
    if (tid < 36) {
        float s = red[0][tid] + red[1][tid] + red[2][tid] + red[3][tid];
        int h = 0, i = tid;
        while (i >= HOPS - h) { i -= (HOPS - h); ++h; }
        int g = h + i;
        aat[b * 64 + h * 8 + g] = s;
        aat[b * 64 + g * 8 + h] = s;
    }
}

// ---------------- K4: penal = sum((AAT - I)^2) ----------------
__global__ __launch_bounds__(256)
void k4_penal(const float* __restrict__ aat, float* __restrict__ out)
{
    const int tid = threadIdx.x;
    float s = 0.0f;
    for (int i = tid; i < B_ * 64; i += 256) {
        int hg = i & 63;
        float d = aat[i] - (((hg >> 3) == (hg & 7)) ? 1.0f : 0.0f);
        s = fmaf(d, d, s);
    }
    s = waveSum(s);
    __shared__ float red[4];
    if ((tid & 63) == 0) red[tid >> 6] = s;
    __syncthreads();
    if (tid == 0) out[OFF_PENAL] = red[0] + red[1] + red[2] + red[3];
}

extern "C" void kernel_launch(void* const* d_in, const int* in_sizes, int n_in,
                              void* d_out, int out_size, void* d_ws, size_t ws_size,
                              hipStream_t stream) {
    const float* node  = (const float*)d_in[0];
    const float* neigh = (const float*)d_in[1];
    const int*   nnum  = (const int*)d_in[2];   // reads low 32 bits of elem 0: ok for i32 or i64 LE
    const float* W1    = (const float*)d_in[3];
    const float* b1    = (const float*)d_in[4];
    const float* W2    = (const float*)d_in[5];
    const float* b2    = (const float*)d_in[6];
    float* out   = (float*)d_out;
    float* stats = (float*)d_ws;          // 512*2 floats
    float* aat   = stats + 1024;          // 64*64 floats

    k1_s2 <<<B_ * 16, 256, 0, stream>>>(node, neigh, nnum, W1, b1, W2, b2, out);
    k2_stats<<<B_ * HOPS, 256, 0, stream>>>(out, stats);
    k3_soft <<<B_, 256, 0, stream>>>(out, stats, aat);
    k4_penal<<<1, 256, 0, stream>>>(aat, out);
}

// Round 3
// 140.910 us; speedup vs baseline: 1.6190x; 1.2316x over previous
//
#include <hip/hip_runtime.h>
#include <hip/hip_bf16.h>
#include <math.h>

#define HID 128
#define ATT 64
#define HOPS 8
#define T_ 64
#define N_ 64
#define B_ 64
#define L_ 4096

typedef __attribute__((ext_vector_type(8))) short bf16x8;
typedef __attribute__((ext_vector_type(4))) float f32x4;

static constexpr size_t OFF_A     = (size_t)B_ * N_ * T_;              // 262144
static constexpr size_t OFF_NEIGH = OFF_A + (size_t)B_ * HOPS * L_;    // 2359296
static constexpr size_t OFF_PENAL = OFF_NEIGH + (size_t)B_ * L_ * HID; // 35913728

__device__ __forceinline__ short f2bf(float x) {
    __hip_bfloat16 h = __float2bfloat16(x);
    return __builtin_bit_cast(short, h);
}

// ---------------- K1: MFMA s1-GEMM fused with H, neigh copy, tanh, s2 ----------------
// Per block: 256 rows of one batch. 4 waves; wave handles 16-row tile x 64 cols,
// 4 row-group iterations. K-convention for both A and B frags: k = ks*32 + g*8 + i
// (any consistent bijection is correct; D layout is the m89-verified one).
__global__ __launch_bounds__(256, 3)
void k1_mfma(const float* __restrict__ node, const float* __restrict__ neigh,
             const int* __restrict__ nnum, const float* __restrict__ W1,
             const float* __restrict__ b1, const float* __restrict__ W2,
             const float* __restrict__ b2, float* __restrict__ out)
{
    const int tid  = threadIdx.x;
    const int w    = tid >> 6;
    const int lane = tid & 63;
    const int c    = lane & 15;
    const int g    = lane >> 4;

    const int b  = blockIdx.x >> 4;
    const int l0 = (blockIdx.x & 15) << 8;

    const float inv_scale = rsqrtf((float)nnum[0]);

    // persistent W1 fragments (B operand): lane holds W1[col=cf*16+c][k=ks*32+g*8+i]
    bf16x8 wf[4][4];
    #pragma unroll
    for (int cf = 0; cf < 4; ++cf) {
        const float* wrow = W1 + (cf * 16 + c) * HID;
        #pragma unroll
        for (int ks = 0; ks < 4; ++ks) {
            const float* p = wrow + ks * 32 + g * 8;
            union { bf16x8 v; short s[8]; } u;
            #pragma unroll
            for (int i = 0; i < 8; ++i) u.s[i] = f2bf(p[i]);
            wf[cf][ks] = u.v;
        }
    }
    float b1v[4], w2v[4][8];
    #pragma unroll
    for (int cf = 0; cf < 4; ++cf) {
        b1v[cf] = b1[cf * 16 + c];
        #pragma unroll
        for (int h = 0; h < 8; ++h) w2v[cf][h] = W2[h * ATT + cf * 16 + c];
    }
    const float b2v = b2[c & 7];

    // node row for this lane's A-fragment rows: (l0 + it*64 + w*16 + c) % 64 = w*16+c
    const float* nd = node + ((size_t)b * T_ + (w * 16 + c)) * HID;

    const size_t rowbase = ((size_t)b * L_ + l0 + w * 16 + c) * HID;
    const float* np = neigh + rowbase;
    float*       cp = out + OFF_NEIGH + rowbase;
    float*       s2base = out + OFF_A + (size_t)b * HOPS * L_;

    #pragma unroll 1
    for (int it = 0; it < 4; ++it) {
        const int    rb  = l0 + it * 64 + w * 16;   // output-tile row base
        const float* npi = np + (size_t)it * 64 * HID;
        float*       cpi = cp + (size_t)it * 64 * HID;

        f32x4 acc[4];
        #pragma unroll
        for (int cf = 0; cf < 4; ++cf) acc[cf] = (f32x4){0.f, 0.f, 0.f, 0.f};

        // prefetch ks=0
        float4 a0 = *(const float4*)(npi + g * 8);
        float4 a1 = *(const float4*)(npi + g * 8 + 4);
        float4 n0 = *(const float4*)(nd  + g * 8);
        float4 n1 = *(const float4*)(nd  + g * 8 + 4);

        #pragma unroll
        for (int ks = 0; ks < 4; ++ks) {
            float4 p0, p1, q0, q1;
            if (ks < 3) {
                const int d = (ks + 1) * 32 + g * 8;
                p0 = *(const float4*)(npi + d);
                p1 = *(const float4*)(npi + d + 4);
                q0 = *(const float4*)(nd  + d);
                q1 = *(const float4*)(nd  + d + 4);
            }
            // copy-out current 32B (net WRITE stays 128 MB; full line coverage per wave)
            *(float4*)(cpi + ks * 32 + g * 8)     = a0;
            *(float4*)(cpi + ks * 32 + g * 8 + 4) = a1;

            union { bf16x8 v; short s[8]; } af;
            af.s[0] = f2bf(a0.x * n0.x); af.s[1] = f2bf(a0.y * n0.y);
            af.s[2] = f2bf(a0.z * n0.z); af.s[3] = f2bf(a0.w * n0.w);
            af.s[4] = f2bf(a1.x * n1.x); af.s[5] = f2bf(a1.y * n1.y);
            af.s[6] = f2bf(a1.z * n1.z); af.s[7] = f2bf(a1.w * n1.w);
            #pragma unroll
            for (int cf = 0; cf < 4; ++cf)
                acc[cf] = __builtin_amdgcn_mfma_f32_16x16x32_bf16(af.v, wf[cf][ks], acc[cf], 0, 0, 0);
            a0 = p0; a1 = p1; n0 = q0; n1 = q1;
        }

        // epilogue: lane holds s1[rb + g*4 + j][a = cf*16 + c] in acc[cf][j]
        #pragma unroll
        for (int j = 0; j < 4; ++j) {
            float p[8];
            #pragma unroll
            for (int h = 0; h < 8; ++h) p[h] = 0.f;
            #pragma unroll
            for (int cf = 0; cf < 4; ++cf) {
                float th = (acc[cf][j] + b1v[cf]) * inv_scale;
                th = 1.0f - 2.0f / (__expf(2.0f * th) + 1.0f);   // tanh, inf-safe
                #pragma unroll
                for (int h = 0; h < 8; ++h) p[h] = fmaf(th, w2v[cf][h], p[h]);
            }
            #pragma unroll
            for (int m = 1; m < 16; m <<= 1) {
                #pragma unroll
                for (int h = 0; h < 8; ++h) p[h] += __shfl_xor(p[h], m, 64);
            }
            // static-indexed predicated stores (avoid runtime-indexed p[] -> scratch)
            #pragma unroll
            for (int h = 0; h < 8; ++h)
                if (c == h)
                    s2base[(size_t)h * L_ + rb + g * 4 + j] = p[h] + b2v;
        }
    }
}

// ---------------- reductions helpers ----------------
__device__ __forceinline__ float waveMax(float v) {
    #pragma unroll
    for (int o = 32; o > 0; o >>= 1) v = fmaxf(v, __shfl_xor(v, o));
    return v;
}
__device__ __forceinline__ float waveSum(float v) {
    #pragma unroll
    for (int o = 32; o > 0; o >>= 1) v += __shfl_xor(v, o);
    return v;
}

// ---------------- K2: per-(b,h) softmax stats + zero aat accumulators ----------------
__global__ __launch_bounds__(256)
void k2_stats(const float* __restrict__ out, float* __restrict__ stats, float* __restrict__ aat)
{
    const int bh = blockIdx.x;                         // 0..511
    const int tid = threadIdx.x;
    if (bh == 0) {
        for (int i = tid; i < B_ * 36; i += 256) aat[i] = 0.f;
    }
    const float* row = out + OFF_A + (size_t)bh * L_;
    __shared__ float red[8];
    float m = -3.4e38f;
    for (int i = tid; i < L_; i += 256) m = fmaxf(m, row[i]);
    m = waveMax(m);
    if ((tid & 63) == 0) red[tid >> 6] = m;
    __syncthreads();
    const float M = fmaxf(fmaxf(red[0], red[1]), fmaxf(red[2], red[3]));
    float s = 0.0f;
    for (int i = tid; i < L_; i += 256) s += __expf(row[i] - M);
    s = waveSum(s);
    if ((tid & 63) == 0) red[4 + (tid >> 6)] = s;
    __syncthreads();
    if (tid == 0) {
        stats[bh * 2]     = M;
        stats[bh * 2 + 1] = red[4] + red[5] + red[6] + red[7];
    }
}

// ---------------- K3: in-place A = softmax, BW, AAT upper-tri partials (atomic) -------
__global__ __launch_bounds__(256)
void k3_soft(float* __restrict__ out, const float* __restrict__ stats, float* __restrict__ aat)
{
    const int blk = blockIdx.x;        // 256 blocks, 4 per batch
    const int b   = blk >> 2;
    const int l0  = (blk & 3) << 10;   // 1024 l's each
    const int tid = threadIdx.x;
    float* A0 = out + OFF_A + (size_t)b * HOPS * L_;
    float* BW = out + (size_t)b * L_;
    float M[HOPS], R[HOPS];
    #pragma unroll
    for (int hh = 0; hh < HOPS; ++hh) {
        M[hh] = stats[(b * HOPS + hh) * 2];
        R[hh] = 1.0f / stats[(b * HOPS + hh) * 2 + 1];
    }
    float p[36];
    #pragma unroll
    for (int i = 0; i < 36; ++i) p[i] = 0.0f;
    for (int l = l0 + tid; l < l0 + 1024; l += 256) {
        float e[HOPS]; float srow = 0.0f;
        #pragma unroll
        for (int hh = 0; hh < HOPS; ++hh) {
            float v = __expf(A0[hh * L_ + l] - M[hh]) * R[hh];
            e[hh] = v; srow += v;
        }
        #pragma unroll
        for (int hh = 0; hh < HOPS; ++hh) A0[hh * L_ + l] = e[hh];
        BW[l] = srow;
        int i = 0;
        #pragma unroll
        for (int hh = 0; hh < HOPS; ++hh) {
            #pragma unroll
            for (int gg = hh; gg < HOPS; ++gg) { p[i] = fmaf(e[hh], e[gg], p[i]); ++i; }
        }
    }
    #pragma unroll
    for (int i = 0; i < 36; ++i) p[i] = waveSum(p[i]);
    __shared__ float red[4][36];
    const int wv = tid >> 6, ln = tid & 63;
    if (ln == 0) {
        #pragma unroll
        for (int i = 0; i < 36; ++i) red[wv][i] = p[i];
    }
    __syncthreads();
    if (tid < 36) {
        float s = red[0][tid] + red[1][tid] + red[2][tid] + red[3][tid];
        atomicAdd(&aat[b * 36 + tid], s);
    }
}

// ---------------- K4: penal = sum_b sum((AAT_b - I)^2), off-diag counted twice --------
__global__ __launch_bounds__(256)
void k4_penal(const float* __restrict__ aat, float* __restrict__ out)
{
    const int tid = threadIdx.x;
    float s = 0.0f;
    for (int i = tid; i < B_ * 36; i += 256) {
        int r = i % 36;
        bool dg = (r == 0) | (r == 8) | (r == 15) | (r == 21) |
                  (r == 26) | (r == 30) | (r == 33) | (r == 35);
        float d = aat[i] - (dg ? 1.0f : 0.0f);
        float q = d * d;
        s += dg ? q : 2.0f * q;
    }
    s = waveSum(s);
    __shared__ float red[4];
    if ((tid & 63) == 0) red[tid >> 6] = s;
    __syncthreads();
    if (tid == 0) out[OFF_PENAL] = red[0] + red[1] + red[2] + red[3];
}

extern "C" void kernel_launch(void* const* d_in, const int* in_sizes, int n_in,
                              void* d_out, int out_size, void* d_ws, size_t ws_size,
                              hipStream_t stream) {
    const float* node  = (const float*)d_in[0];
    const float* neigh = (const float*)d_in[1];
    const int*   nnum  = (const int*)d_in[2];   // low 32 bits of elem 0 (LE, value in [1,64))
    const float* W1    = (const float*)d_in[3];
    const float* b1    = (const float*)d_in[4];
    const float* W2    = (const float*)d_in[5];
    const float* b2    = (const float*)d_in[6];
    float* out   = (float*)d_out;
    float* stats = (float*)d_ws;          // 512*2 floats
    float* aat   = stats + 1024;          // 64*36 floats (upper-tri, accumulated)

    k1_mfma <<<B_ * 16, 256, 0, stream>>>(node, neigh, nnum, W1, b1, W2, b2, out);
    k2_stats<<<B_ * HOPS, 256, 0, stream>>>(out, stats, aat);
    k3_soft <<<256, 256, 0, stream>>>(out, stats, aat);
    k4_penal<<<1, 256, 0, stream>>>(aat, out);
}

// Round 4
// 101.520 us; speedup vs baseline: 2.2471x; 1.3880x over previous
//
#include <hip/hip_runtime.h>
#include <hip/hip_bf16.h>
#include <math.h>

#define HID 128
#define ATT 64
#define HOPS 8
#define T_ 64
#define N_ 64
#define B_ 64
#define L_ 4096

typedef __attribute__((ext_vector_type(8))) short bf16x8;
typedef __attribute__((ext_vector_type(4))) float f32x4;

static constexpr size_t OFF_A     = (size_t)B_ * N_ * T_;              // 262144
static constexpr size_t OFF_NEIGH = OFF_A + (size_t)B_ * HOPS * L_;    // 2359296
static constexpr size_t OFF_PENAL = OFF_NEIGH + (size_t)B_ * L_ * HID; // 35913728

__device__ __forceinline__ unsigned pkbf(float lo, float hi) {
    unsigned a = (unsigned)(unsigned short)__builtin_bit_cast(unsigned short, __float2bfloat16(lo));
    unsigned b = (unsigned)(unsigned short)__builtin_bit_cast(unsigned short, __float2bfloat16(hi));
    return a | (b << 16);
}
__device__ __forceinline__ short f2bf(float x) {
    return __builtin_bit_cast(short, __float2bfloat16(x));
}

// ---------------- K1: pipelined MFMA s1->tanh->s2, fused H + neigh copy ----------------
// 256 threads = 4 waves; wave owns 16 rows x 4 its = 64 rows; block = 256 rows.
// Pipeline: neigh row loads for it+1 issued one full iteration ahead (load->use
// distance ~ stores+cvt+MFMA+epilogue >> 900cy HBM latency). node in regs (invariant).
// W1 in LDS as bf16 B-frags (stride 136 shorts -> 2-way bank alias, free).
// Epilogue: tanh tile -> per-wave LDS -> A-frag reads -> MFMA x W2 -> s2 in C-layout.
__global__ __launch_bounds__(256, 3)
void k1_mfma(const float* __restrict__ node, const float* __restrict__ neigh,
             const int* __restrict__ nnum, const float* __restrict__ W1,
             const float* __restrict__ b1, const float* __restrict__ W2,
             const float* __restrict__ b2, float* __restrict__ out)
{
    __shared__ unsigned w1lds[64 * 68];      // W1 bf16 [a][k], row stride 68 u32 (136 sh)
    __shared__ short    thlds[4][16 * 72];   // per-wave tanh tile, row stride 72 shorts

    const int tid  = threadIdx.x;
    const int w    = tid >> 6;
    const int lane = tid & 63;
    const int c    = lane & 15;
    const int g    = lane >> 4;

    const int b  = blockIdx.x >> 4;
    const int l0 = (blockIdx.x & 15) << 8;

    const float* nd = node + ((size_t)b * T_ + (w * 16 + c)) * HID;
    const size_t rowbase = ((size_t)b * L_ + l0 + w * 16 + c) * HID;
    const float* np = neigh + rowbase;
    float*       cp = out + OFF_NEIGH + rowbase;
    float*       s2base = out + OFF_A + (size_t)b * HOPS * L_;

    // ---- issue node + it0 neigh loads first (overlap with W1 staging) ----
    float4 n[8], abuf[8];
    #pragma unroll
    for (int ks = 0; ks < 4; ++ks) {
        n[2*ks]      = *(const float4*)(nd + ks*32 + g*8);
        n[2*ks+1]    = *(const float4*)(nd + ks*32 + g*8 + 4);
        abuf[2*ks]   = *(const float4*)(np + ks*32 + g*8);
        abuf[2*ks+1] = *(const float4*)(np + ks*32 + g*8 + 4);
    }

    // ---- stage W1 into LDS as bf16 ----
    {
        const int a = tid >> 2, q = tid & 3;
        const float* src = W1 + a * HID + q * 32;
        float x[32];
        #pragma unroll
        for (int i = 0; i < 8; ++i) *(float4*)&x[i*4] = *(const float4*)(src + i*4);
        unsigned* dst = &w1lds[a * 68 + q * 16];
        #pragma unroll
        for (int i = 0; i < 16; ++i) dst[i] = pkbf(x[2*i], x[2*i+1]);
    }
    __syncthreads();

    const float inv_scale = rsqrtf((float)nnum[0]);

    // W2 as B-fragments (bf16): lane (c,g) holds B[k=ks2*32+g*8+i][col=c] = W2[c][k], c<8
    bf16x8 wf2[2];
    #pragma unroll
    for (int ks2 = 0; ks2 < 2; ++ks2) {
        union { bf16x8 v; unsigned u[4]; } t;
        #pragma unroll
        for (int i = 0; i < 4; ++i) {
            float lo = (c < 8) ? W2[c*64 + ks2*32 + g*8 + 2*i]     : 0.f;
            float hi = (c < 8) ? W2[c*64 + ks2*32 + g*8 + 2*i + 1] : 0.f;
            t.u[i] = pkbf(lo, hi);
        }
        wf2[ks2] = t.v;
    }
    float b1v[4];
    #pragma unroll
    for (int cf = 0; cf < 4; ++cf) b1v[cf] = b1[cf*16 + c];
    const float b2v = (c < 8) ? b2[c] : 0.f;

    const bf16x8* wptr = reinterpret_cast<const bf16x8*>(&w1lds[c * 68 + g * 4]);
    short* thw = thlds[w];

    #pragma unroll
    for (int it = 0; it < 4; ++it) {
        const int rb = l0 + it * 64 + w * 16;
        float* cpi = cp + (size_t)it * 64 * HID;

        // consume abuf: copy-out stores + H product -> bf16 A-frags
        bf16x8 af[4];
        #pragma unroll
        for (int ks = 0; ks < 4; ++ks) {
            *(float4*)(cpi + ks*32 + g*8)     = abuf[2*ks];
            *(float4*)(cpi + ks*32 + g*8 + 4) = abuf[2*ks+1];
            const float4 a0 = abuf[2*ks], a1 = abuf[2*ks+1];
            const float4 n0 = n[2*ks],    n1 = n[2*ks+1];
            union { bf16x8 v; unsigned u[4]; } t;
            t.u[0] = pkbf(a0.x*n0.x, a0.y*n0.y);
            t.u[1] = pkbf(a0.z*n0.z, a0.w*n0.w);
            t.u[2] = pkbf(a1.x*n1.x, a1.y*n1.y);
            t.u[3] = pkbf(a1.z*n1.z, a1.w*n1.w);
            af[ks] = t.v;
        }
        // prefetch next it's neigh row (one full iteration of latency cover)
        if (it < 3) {
            const float* nx = np + (size_t)(it+1) * 64 * HID;
            #pragma unroll
            for (int ks = 0; ks < 4; ++ks) {
                abuf[2*ks]   = *(const float4*)(nx + ks*32 + g*8);
                abuf[2*ks+1] = *(const float4*)(nx + ks*32 + g*8 + 4);
            }
        }
        // s1 GEMM: 16 MFMA, B-frags streamed from LDS (imm-offset ds_read_b128)
        f32x4 acc[4];
        #pragma unroll
        for (int cf = 0; cf < 4; ++cf) acc[cf] = (f32x4){0.f,0.f,0.f,0.f};
        #pragma unroll
        for (int cf = 0; cf < 4; ++cf) {
            #pragma unroll
            for (int ks = 0; ks < 4; ++ks)
                acc[cf] = __builtin_amdgcn_mfma_f32_16x16x32_bf16(af[ks], wptr[cf*272 + ks*4], acc[cf], 0, 0, 0);
        }
        // epilogue: tanh -> LDS tile -> A-frags -> s2 MFMA
        #pragma unroll
        for (int cf = 0; cf < 4; ++cf) {
            #pragma unroll
            for (int j = 0; j < 4; ++j) {
                float th = (acc[cf][j] + b1v[cf]) * inv_scale;
                th = 1.0f - 2.0f / (__expf(2.0f * th) + 1.0f);   // tanh, inf-safe
                thw[(g*4+j)*72 + cf*16 + c] = f2bf(th);
            }
        }
        f32x4 acc2 = (f32x4){0.f,0.f,0.f,0.f};
        #pragma unroll
        for (int ks2 = 0; ks2 < 2; ++ks2) {
            bf16x8 pa = *reinterpret_cast<const bf16x8*>(&thw[c*72 + ks2*32 + g*8]);
            acc2 = __builtin_amdgcn_mfma_f32_16x16x32_bf16(pa, wf2[ks2], acc2, 0, 0, 0);
        }
        if (c < 8) {
            #pragma unroll
            for (int j = 0; j < 4; ++j)
                s2base[(size_t)c * L_ + rb + g*4 + j] = acc2[j] + b2v;
        }
    }
}

// ---------------- reductions helpers ----------------
__device__ __forceinline__ float waveMax(float v) {
    #pragma unroll
    for (int o = 32; o > 0; o >>= 1) v = fmaxf(v, __shfl_xor(v, o));
    return v;
}
__device__ __forceinline__ float waveSum(float v) {
    #pragma unroll
    for (int o = 32; o > 0; o >>= 1) v += __shfl_xor(v, o);
    return v;
}

// ---------------- K2: per-(b,h) softmax stats + zero aat accumulators ----------------
__global__ __launch_bounds__(256)
void k2_stats(const float* __restrict__ out, float* __restrict__ stats, float* __restrict__ aat)
{
    const int bh = blockIdx.x;                         // 0..511
    const int tid = threadIdx.x;
    if (bh == 0) {
        for (int i = tid; i < B_ * 36; i += 256) aat[i] = 0.f;
    }
    const float* row = out + OFF_A + (size_t)bh * L_;
    __shared__ float red[8];
    float m = -3.4e38f;
    for (int i = tid; i < L_; i += 256) m = fmaxf(m, row[i]);
    m = waveMax(m);
    if ((tid & 63) == 0) red[tid >> 6] = m;
    __syncthreads();
    const float M = fmaxf(fmaxf(red[0], red[1]), fmaxf(red[2], red[3]));
    float s = 0.0f;
    for (int i = tid; i < L_; i += 256) s += __expf(row[i] - M);
    s = waveSum(s);
    if ((tid & 63) == 0) red[4 + (tid >> 6)] = s;
    __syncthreads();
    if (tid == 0) {
        stats[bh * 2]     = M;
        stats[bh * 2 + 1] = red[4] + red[5] + red[6] + red[7];
    }
}

// ---------------- K3: in-place A = softmax, BW, AAT upper-tri partials (atomic) -------
__global__ __launch_bounds__(256)
void k3_soft(float* __restrict__ out, const float* __restrict__ stats, float* __restrict__ aat)
{
    const int blk = blockIdx.x;        // 256 blocks, 4 per batch
    const int b   = blk >> 2;
    const int l0  = (blk & 3) << 10;   // 1024 l's each
    const int tid = threadIdx.x;
    float* A0 = out + OFF_A + (size_t)b * HOPS * L_;
    float* BW = out + (size_t)b * L_;
    float M[HOPS], R[HOPS];
    #pragma unroll
    for (int hh = 0; hh < HOPS; ++hh) {
        M[hh] = stats[(b * HOPS + hh) * 2];
        R[hh] = 1.0f / stats[(b * HOPS + hh) * 2 + 1];
    }
    float p[36];
    #pragma unroll
    for (int i = 0; i < 36; ++i) p[i] = 0.0f;
    for (int l = l0 + tid; l < l0 + 1024; l += 256) {
        float e[HOPS]; float srow = 0.0f;
        #pragma unroll
        for (int hh = 0; hh < HOPS; ++hh) {
            float v = __expf(A0[hh * L_ + l] - M[hh]) * R[hh];
            e[hh] = v; srow += v;
        }
        #pragma unroll
        for (int hh = 0; hh < HOPS; ++hh) A0[hh * L_ + l] = e[hh];
        BW[l] = srow;
        int i = 0;
        #pragma unroll
        for (int hh = 0; hh < HOPS; ++hh) {
            #pragma unroll
            for (int gg = hh; gg < HOPS; ++gg) { p[i] = fmaf(e[hh], e[gg], p[i]); ++i; }
        }
    }
    #pragma unroll
    for (int i = 0; i < 36; ++i) p[i] = waveSum(p[i]);
    __shared__ float red[4][36];
    const int wv = tid >> 6, ln = tid & 63;
    if (ln == 0) {
        #pragma unroll
        for (int i = 0; i < 36; ++i) red[wv][i] = p[i];
    }
    __syncthreads();
    if (tid < 36) {
        float s = red[0][tid] + red[1][tid] + red[2][tid] + red[3][tid];
        atomicAdd(&aat[b * 36 + tid], s);
    }
}

// ---------------- K4: penal = sum_b sum((AAT_b - I)^2), off-diag counted twice --------
__global__ __launch_bounds__(256)
void k4_penal(const float* __restrict__ aat, float* __restrict__ out)
{
    const int tid = threadIdx.x;
    float s = 0.0f;
    for (int i = tid; i < B_ * 36; i += 256) {
        int r = i % 36;
        bool dg = (r == 0) | (r == 8) | (r == 15) | (r == 21) |
                  (r == 26) | (r == 30) | (r == 33) | (r == 35);
        float d = aat[i] - (dg ? 1.0f : 0.0f);
        float q = d * d;
        s += dg ? q : 2.0f * q;
    }
    s = waveSum(s);
    __shared__ float red[4];
    if ((tid & 63) == 0) red[tid >> 6] = s;
    __syncthreads();
    if (tid == 0) out[OFF_PENAL] = red[0] + red[1] + red[2] + red[3];
}

extern "C" void kernel_launch(void* const* d_in, const int* in_sizes, int n_in,
                              void* d_out, int out_size, void* d_ws, size_t ws_size,
                              hipStream_t stream) {
    const float* node  = (const float*)d_in[0];
    const float* neigh = (const float*)d_in[1];
    const int*   nnum  = (const int*)d_in[2];   // low 32 bits of elem 0 (LE, value in [1,64))
    const float* W1    = (const float*)d_in[3];
    const float* b1    = (const float*)d_in[4];
    const float* W2    = (const float*)d_in[5];
    const float* b2    = (const float*)d_in[6];
    float* out   = (float*)d_out;
    float* stats = (float*)d_ws;          // 512*2 floats
    float* aat   = stats + 1024;          // 64*36 floats (upper-tri, accumulated)

    k1_mfma <<<B_ * 16, 256, 0, stream>>>(node, neigh, nnum, W1, b1, W2, b2, out);
    k2_stats<<<B_ * HOPS, 256, 0, stream>>>(out, stats, aat);
    k3_soft <<<256, 256, 0, stream>>>(out, stats, aat);
    k4_penal<<<1, 256, 0, stream>>>(aat, out);
}